// Round 1
// baseline (1074.995 us; speedup 1.0000x reference)
//
#include <hip/hip_runtime.h>
#include <math.h>

// ODE-RNN persistent kernel, round 12: 4-way N-split + register-resident Whh.
// Diagnosis (R11 counters): MfmaUtil 16%, VALU 39%, HBM 2%, ~45% idle ->
// L2-BW-bound streaming Whh (512KB/WG/step at M=4 row utilization).
// New decomposition: 64 groups x 16 rows; each group has 4 sibling WGs
// (bid = s*64+g, same-XCD heuristic) computing a 128-wide N-slice of the
// RNN cell with M=16 MFMA. Per-WG weight slice = whh[:,slice] = 8 half8
// frags/lane (32 VGPR) + wih 1 frag -> fully hoisted; NO per-step L2
// weight streaming. Once per step the 4 siblings exchange their fp16
// h-slices (4KB each) via a double-buffered global buffer:
//   stores/loads = relaxed AGENT atomics (coherent point, cross-XCD safe)
//   flags = monotonic counters, RELEASE fetch_add after barrier-drained
//   stores, ACQUIRE polls. WAR safety of 2-buffer: posting flag(t) implies
//   the poster observed all siblings' flag(t-1), which implies their
//   step-(t-2) reads of this parity buffer are complete.
// feval/Euler computed redundantly by all 4 siblings (full y stays local;
// compute is not the bottleneck). All 256 WGs co-resident (49KB LDS,
// <=128 VGPR, 16 waves) -> no spin deadlock. Euler (1 feval) kept from R8.

#define NWG  256
#define NTHR 1024
#define Tn   100
#define Dn   64
#define Hn   512
#define Fn   50
#define YP   528   // fp16 pitch: 264 dwords == 8 mod 32 -> uniform-depth A-reads
#define XP   80
#define GPp  80

typedef __attribute__((ext_vector_type(8))) _Float16 half8;
typedef __attribute__((ext_vector_type(4))) float f32x4;

__device__ __forceinline__ float my_tanh(float v) {
    float e = __expf(2.0f * v);
    return 1.0f - 2.0f / (e + 1.0f);   // exact 0 at v=0
}

// f(y) = tanh(tanh(y@W1^T + b1)@W2^T + b2) * scale_row, M=16 rows.
// Wave w: GEMM1 job (kh=w>>2, nt1=w&3, 4 MFMA, B in w1f); GEMM2 n-tiles
// {w, w+16} (B in w2f). kout[i][r] valid in ALL lanes (row = q*4+r).
__device__ __forceinline__ void feval(
    const _Float16* arg, const half8 w1f[4], const half8 w2f[2][2],
    float* gp, _Float16* gbf, const float b1v, const float b2v[2],
    const float scv[4], int w, int lane, int tid, float kout[2][4])
{
    const int r16 = lane & 15, q = lane >> 4;
    const int kh = w >> 2, nt1 = w & 3;
    f32x4 acc = {0.f, 0.f, 0.f, 0.f};
    const _Float16* arow = arg + r16 * YP + q * 8;
#pragma unroll
    for (int t = 0; t < 4; ++t) {
        half8 a = *(const half8*)(arow + (kh * 4 + t) * 32);
        acc = __builtin_amdgcn_mfma_f32_16x16x32_f16(a, w1f[t], acc, 0, 0, 0);
    }
    // partial: gp[kh][nt1][row][col], row = q*4+r, col = r16, pitch 17
#pragma unroll
    for (int r = 0; r < 4; ++r)
        gp[((kh * 4 + nt1) * 16 + (q * 4 + r)) * 17 + r16] = acc[r];
    __syncthreads();
    {   // mid layer: 16 rows x 64 neurons -> exactly 1024 threads
        const int r = tid >> 6, n = tid & 63;
        const int nt = n >> 4, cc = n & 15;
        float s = gp[((0*4 + nt) * 16 + r) * 17 + cc]
                + gp[((1*4 + nt) * 16 + r) * 17 + cc]
                + gp[((2*4 + nt) * 16 + r) * 17 + cc]
                + gp[((3*4 + nt) * 16 + r) * 17 + cc];
        float gv = (n < Fn) ? my_tanh(s + b1v) : 0.0f;
        gbf[r * GPp + n] = (_Float16)gv;
    }
    __syncthreads();
    half8 af0 = *(const half8*)(gbf + r16 * GPp + q * 8);
    half8 af1 = *(const half8*)(gbf + r16 * GPp + 32 + q * 8);
#pragma unroll
    for (int i = 0; i < 2; ++i) {
        f32x4 c = {0.f, 0.f, 0.f, 0.f};
        c = __builtin_amdgcn_mfma_f32_16x16x32_f16(af0, w2f[i][0], c, 0, 0, 0);
        c = __builtin_amdgcn_mfma_f32_16x16x32_f16(af1, w2f[i][1], c, 0, 0, 0);
#pragma unroll
        for (int r = 0; r < 4; ++r)
            kout[i][r] = my_tanh(c[r] + b2v[i]) * scv[r];
    }
}

extern "C" __global__ void __launch_bounds__(NTHR, 4)
odernn_main(const float* __restrict__ dt, const float* __restrict__ x,
            const float* __restrict__ b_ih, const float* __restrict__ b_hh,
            const float* __restrict__ b1,   const float* __restrict__ b2,
            const float* __restrict__ bl1,  const float* __restrict__ Wmu,
            const float* __restrict__ bmu,
            const _Float16* __restrict__ w1p,  const _Float16* __restrict__ w2p,
            const _Float16* __restrict__ whh,  const _Float16* __restrict__ wih,
            const _Float16* __restrict__ wl1p,
            unsigned* __restrict__ hx, unsigned* __restrict__ flags,
            _Float16* __restrict__ yg, float* __restrict__ out, int defer)
{
    __shared__ __align__(16) _Float16 ybuf[16 * YP];
    __shared__ __align__(16) _Float16 xbuf[16 * XP];
    __shared__ __align__(16) _Float16 gbf[16 * GPp];
    __shared__ __align__(16) float    gp[4 * 4 * 16 * 17];
    __shared__ __align__(16) float    rp[8 * 16 * 17];
    __shared__ float sc_row[16];
    __shared__ float hp[16][16];

    const int tid  = threadIdx.x;
    const int w    = tid >> 6;        // wave 0..15
    const int lane = tid & 63;
    const int r16  = lane & 15, q = lane >> 4;
    const int g    = blockIdx.x & 63; // row group (same-XCD siblings: bid%8 == g%8)
    const int s    = blockIdx.x >> 6; // sibling / N-slice 0..3
    const int row0 = g * 16;
    const int ns0  = s * 128;

    for (int i = tid; i < 16 * YP; i += NTHR) ybuf[i] = (_Float16)0.0f;

    // ---- hoisted, loop-invariant weights (all register-resident) ----
    // RNN: wave w covers slice n-tile (w&7), K-half kh2; 8 whh frags + 1 wih.
    const int kh2 = w >> 3;
    const int ng  = s * 8 + (w & 7);           // global n-tile index (NT=32)
    half8 whf[8];
#pragma unroll
    for (int j = 0; j < 8; ++j) {
        const int kg = kh2 * 8 + j;
        whf[j] = ((const half8*)whh)[((kg * 32 + ng) << 6) + lane];
    }
    const half8 wif = ((const half8*)wih)[((kh2 * 32 + ng) << 6) + lane];

    half8 w1f[4];
    {
        const int kh = w >> 2, nt1 = w & 3;
#pragma unroll
        for (int t = 0; t < 4; ++t) {
            const int kt = kh * 4 + t;
            w1f[t] = ((const half8*)w1p)[(((kt << 2) + nt1) << 6) + lane];
        }
    }
    half8 w2f[2][2];
#pragma unroll
    for (int i = 0; i < 2; ++i) {
        const int nt = w + (i << 4);
        w2f[i][0] = ((const half8*)w2p)[(nt << 6) + lane];
        w2f[i][1] = ((const half8*)w2p)[((32 + nt) << 6) + lane];
    }

    // per-lane constants
    const int   nrnn = ns0 + (w & 7) * 16 + r16;  // RNN output column (lower waves)
    const float bCn  = b_ih[nrnn] + b_hh[nrnn];
    float b2v[2];
    int   ci[2];
#pragma unroll
    for (int i = 0; i < 2; ++i) {
        const int n = (w + i * 16) * 16 + r16;
        b2v[i] = b2[n];
        ci[i]  = n;
    }
    const float b1v  = ((tid & 63) < Fn) ? b1[tid & 63] : 0.0f;
    const float blv  = bl1[w * 16 + r16];  // fallback head only
    const float wmv  = Wmu[w * 16 + r16];
    const float bmu0 = bmu[0];

    unsigned* const myflag = flags + (g * 4 + s);

    // stage x/sc for ts = 0 (16 rows x 64 cols = all 1024 threads)
    {
        const int r = tid >> 6, c = tid & 63;
        xbuf[r * XP + c] = (_Float16)x[((size_t)(row0 + r) * Tn + 0) * Dn + c];
    }
    if (tid < 16) {
        const size_t di = ((size_t)(row0 + tid) * Tn + 0) * 2;
        sc_row[tid] = (dt[di + 1] - dt[di]) * 0.01f;
    }
    __syncthreads();

    float scv[4], kout[2][4], ycur[2][4];
    float xv = 0.f, scn = 0.f;

#pragma unroll 1
    for (int ts = 0; ts < Tn; ++ts) {
        // ---- RNN cell: M=16, N-slice=128, K split across wave pairs ----
        f32x4 acc = {0.f, 0.f, 0.f, 0.f};
        {
            const _Float16* yh = ybuf + r16 * YP + q * 8 + kh2 * 256;
#pragma unroll
            for (int j = 0; j < 8; ++j) {
                half8 a = *(const half8*)(yh + j * 32);
                acc = __builtin_amdgcn_mfma_f32_16x16x32_f16(a, whf[j], acc, 0, 0, 0);
            }
            const _Float16* xh = xbuf + r16 * XP + q * 8 + kh2 * 32;
            half8 ax = *(const half8*)(xh);
            acc = __builtin_amdgcn_mfma_f32_16x16x32_f16(ax, wif, acc, 0, 0, 0);
        }
        if (w >= 8) {   // upper K-half: publish partial
#pragma unroll
            for (int r = 0; r < 4; ++r)
                rp[((w - 8) * 16 + q * 4 + r) * 17 + r16] = acc[r];
        }
        __syncthreads();   // B1: rp visible; all ybuf/xbuf A-reads done
        if (w < 8) {       // reduce pair, bias, tanh -> h slice into ybuf
#pragma unroll
            for (int r = 0; r < 4; ++r) {
                float pre = acc[r] + rp[(w * 16 + q * 4 + r) * 17 + r16] + bCn;
                ybuf[(q * 4 + r) * YP + nrnn] = (_Float16)my_tanh(pre);
            }
        }
        // prefetch next x/dt into regs (latency overlapped until B2 drain)
        {
            const int tsn = (ts + 1 < Tn) ? ts + 1 : ts;
            const int r = tid >> 6, c = tid & 63;
            xv = x[((size_t)(row0 + r) * Tn + tsn) * Dn + c];
            if (tid < 16) {
                const size_t di = ((size_t)(row0 + tid) * Tn + tsn) * 2;
                scn = (dt[di + 1] - dt[di]) * 0.01f;
            }
        }
        __syncthreads();   // B2: h slice in ybuf

        // ---- exchange h slices among the 4 siblings ----
        const unsigned pb = (unsigned)(ts & 1);
        {   // own slice: ybuf dwords -> hx (agent-scope write-through)
            const int r = tid >> 6, c6 = tid & 63;
            const unsigned* ybd = (const unsigned*)ybuf;
            unsigned v = ybd[r * (YP / 2) + s * 64 + c6];
            __hip_atomic_store(hx + ((pb * 256u + (unsigned)(g * 4 + s)) * 1024u + tid),
                               v, __ATOMIC_RELAXED, __HIP_MEMORY_SCOPE_AGENT);
        }
        __syncthreads();   // B3: barrier drain (vmcnt0) -> all stores at coherence pt
        if (tid == 0)
            __hip_atomic_fetch_add(myflag, 1u, __ATOMIC_RELEASE,
                                   __HIP_MEMORY_SCOPE_AGENT);
        if (tid >= 1 && tid <= 3) {
            unsigned* f = flags + (g * 4 + ((s + tid) & 3));
            while (__hip_atomic_load(f, __ATOMIC_ACQUIRE,
                                     __HIP_MEMORY_SCOPE_AGENT) < (unsigned)(ts + 1)) {}
        }
        __syncthreads();   // B4: all sibling flags observed
        {   // pull 3 remote slices (coherent loads) -> ybuf
            const int r = tid >> 6, c6 = tid & 63;
            unsigned* ybd = (unsigned*)ybuf;
#pragma unroll
            for (int o = 1; o < 4; ++o) {
                const int so = (s + o) & 3;
                unsigned v = __hip_atomic_load(
                    hx + ((pb * 256u + (unsigned)(g * 4 + so)) * 1024u + tid),
                    __ATOMIC_RELAXED, __HIP_MEMORY_SCOPE_AGENT);
                ybd[r * (YP / 2) + so * 64 + c6] = v;
            }
        }
        __syncthreads();   // B5: full y0 in ybuf

        // load y0 into update regs (GEMM2 output mapping) + per-row scales
#pragma unroll
        for (int i = 0; i < 2; ++i)
#pragma unroll
            for (int r = 0; r < 4; ++r)
                ycur[i][r] = (float)ybuf[(q * 4 + r) * YP + ci[i]];
#pragma unroll
        for (int r = 0; r < 4; ++r) scv[r] = sc_row[q * 4 + r];

        // ---- ODE: Euler step, h = 1 (feval has internal syncs B6, B7) ----
        feval(ybuf, w1f, w2f, gp, gbf, b1v, b2v, scv, w, lane, tid, kout);

        // y_new = y + k1 (all waves cover full width); stage next x/sc
#pragma unroll
        for (int i = 0; i < 2; ++i)
#pragma unroll
            for (int r = 0; r < 4; ++r) {
                ycur[i][r] += kout[i][r];
                ybuf[(q * 4 + r) * YP + ci[i]] = (_Float16)ycur[i][r];
            }
        {
            const int r = tid >> 6, c = tid & 63;
            xbuf[r * XP + c] = (_Float16)xv;
        }
        if (tid < 16) sc_row[tid] = scn;
        __syncthreads();   // B8: y_new + x + sc visible

        if (defer) {
            // store this WG's N-slice of y (1 dword/thread, coalesced)
            const int r = tid >> 6, c6 = tid & 63;
            const unsigned* ybd = (const unsigned*)ybuf;
            unsigned v = ybd[r * (YP / 2) + s * 64 + c6];
            *(unsigned*)(yg + (((size_t)(row0 + r) * Tn + ts) * 512 + ns0 + c6 * 2)) = v;
        } else {
            // in-loop head (fallback): wave w -> Wl1 n-tile w, M=16
            f32x4 aH = {0.f, 0.f, 0.f, 0.f};
            const _Float16* yh = ybuf + r16 * YP + q * 8;
#pragma unroll 4
            for (int kt = 0; kt < 16; ++kt) {
                half8 ah = *(const half8*)(yh + kt * 32);
                half8 b  = *(const half8*)(wl1p + ((kt * 16 + w) << 9) + (lane << 3));
                aH = __builtin_amdgcn_mfma_f32_16x16x32_f16(ah, b, aH, 0, 0, 0);
            }
            float pr[4];
#pragma unroll
            for (int r = 0; r < 4; ++r) {
                float pv = fmaxf(aH[r] + blv, 0.0f) * wmv;
#pragma unroll
                for (int o = 1; o < 16; o <<= 1) pv += __shfl_xor(pv, o);
                pr[r] = pv;
            }
            if (r16 == 0) {
#pragma unroll
                for (int r = 0; r < 4; ++r) hp[w][q * 4 + r] = pr[r];
            }
            __syncthreads();
            if (tid < 16) {
                float sum = bmu0;
#pragma unroll
                for (int wv = 0; wv < 16; ++wv) sum += hp[wv][tid];
                out[(size_t)(row0 + tid) * Tn + ts] = sum;
            }
            __syncthreads();
        }
    }
}

// phase-2 head: out[b,t] = relu(y[b,t]@Wl1^T + bl1)@Wmu^T + bmu
// grid = (B/16)*Tn WGs x 256 threads; wave w covers n in [w*64,(w+1)*64)
extern "C" __global__ void __launch_bounds__(256, 4)
odernn_head(const _Float16* __restrict__ yg, const _Float16* __restrict__ wl1p,
            const float* __restrict__ bl1, const float* __restrict__ Wmu,
            const float* __restrict__ bmu, float* __restrict__ out)
{
    __shared__ float hp[4][16];
    const int tid = threadIdx.x, w = tid >> 6, lane = tid & 63;
    const int q = (lane >> 4) & 3;
    const int b0 = (blockIdx.x / Tn) * 16, ts = blockIdx.x % Tn;

    f32x4 acc[4];
#pragma unroll
    for (int j = 0; j < 4; ++j) acc[j] = (f32x4){0.f, 0.f, 0.f, 0.f};
    const _Float16* ap = yg + ((size_t)(b0 + (lane & 15)) * Tn + ts) * 512 + q * 8;
#pragma unroll 4
    for (int kt = 0; kt < 16; ++kt) {
        half8 a = *(const half8*)(ap + kt * 32);
#pragma unroll
        for (int j = 0; j < 4; ++j) {
            half8 b = *(const half8*)(wl1p + ((kt * 16 + w * 4 + j) << 9) + (lane << 3));
            acc[j] = __builtin_amdgcn_mfma_f32_16x16x32_f16(a, b, acc[j], 0, 0, 0);
        }
    }
    float pr[4] = {0.f, 0.f, 0.f, 0.f};
#pragma unroll
    for (int j = 0; j < 4; ++j) {
        const int n = (w * 4 + j) * 16 + (lane & 15);
        const float blv = bl1[n], wmv = Wmu[n];
#pragma unroll
        for (int r = 0; r < 4; ++r)
            pr[r] += fmaxf(acc[j][r] + blv, 0.0f) * wmv;
    }
#pragma unroll
    for (int r = 0; r < 4; ++r)
#pragma unroll
        for (int o = 1; o < 16; o <<= 1) pr[r] += __shfl_xor(pr[r], o);
    if ((lane & 15) == 0) {
        const int gq = lane >> 4;
#pragma unroll
        for (int r = 0; r < 4; ++r) hp[w][gq * 4 + r] = pr[r];
    }
    __syncthreads();
    if (tid < 16)
        out[(size_t)(b0 + tid) * Tn + ts] =
            hp[0][tid] + hp[1][tid] + hp[2][tid] + hp[3][tid] + bmu[0];
}

// pack weights into fp16 MFMA B-fragment order (B[k][n] = W[n][k]) + zero flags
extern "C" __global__ void odernn_init(
    const float* __restrict__ W_ih, const float* __restrict__ W_hh,
    const float* __restrict__ W1,   const float* __restrict__ W2,
    const float* __restrict__ Wl1,
    _Float16* w1p, _Float16* w2p, _Float16* whh, _Float16* wih, _Float16* wl1p,
    unsigned* flags)
{
    const int idx = blockIdx.x * blockDim.x + threadIdx.x;
    const int stride = gridDim.x * blockDim.x;
    // exchange flags must be zero at odernn_main start (each launch/replay)
    for (int p = idx; p < 256; p += stride) flags[p] = 0u;
    // W1: KT=16, NT=4 (N 50->64), K=512
    for (int p = idx; p < 32768; p += stride) {
        int j = p & 7, lane = (p >> 3) & 63, t = p >> 9;
        int nt = t & 3, kt = t >> 2;
        int n = nt * 16 + (lane & 15), k = kt * 32 + ((lane >> 4) << 3) + j;
        w1p[p] = (_Float16)((n < 50) ? W1[n * 512 + k] : 0.f);
    }
    // W2: KT=2 (K 50->64), NT=32, N=512
    for (int p = idx; p < 32768; p += stride) {
        int j = p & 7, lane = (p >> 3) & 63, t = p >> 9;
        int nt = t & 31, kt = t >> 5;
        int n = nt * 16 + (lane & 15), k = kt * 32 + ((lane >> 4) << 3) + j;
        w2p[p] = (_Float16)((k < 50) ? W2[n * 50 + k] : 0.f);
    }
    // Whh: KT=16, NT=32
    for (int p = idx; p < 262144; p += stride) {
        int j = p & 7, lane = (p >> 3) & 63, t = p >> 9;
        int nt = t & 31, kt = t >> 5;
        int n = nt * 16 + (lane & 15), k = kt * 32 + ((lane >> 4) << 3) + j;
        whh[p] = (_Float16)W_hh[n * 512 + k];
    }
    // Wih: KT=2, NT=32, K=64
    for (int p = idx; p < 32768; p += stride) {
        int j = p & 7, lane = (p >> 3) & 63, t = p >> 9;
        int nt = t & 31, kt = t >> 5;
        int n = nt * 16 + (lane & 15), k = kt * 32 + ((lane >> 4) << 3) + j;
        wih[p] = (_Float16)W_ih[n * 64 + k];
    }
    // Wl1: KT=16, NT=16, N=256, K=512
    for (int p = idx; p < 131072; p += stride) {
        int j = p & 7, lane = (p >> 3) & 63, t = p >> 9;
        int nt = t & 15, kt = t >> 4;
        int n = nt * 16 + (lane & 15), k = kt * 32 + ((lane >> 4) << 3) + j;
        wl1p[p] = (_Float16)Wl1[n * 512 + k];
    }
}

extern "C" void kernel_launch(void* const* d_in, const int* in_sizes, int n_in,
                              void* d_out, int out_size, void* d_ws, size_t ws_size,
                              hipStream_t stream)
{
    (void)in_sizes; (void)n_in; (void)out_size;
    const float* dt   = (const float*)d_in[0];
    const float* x    = (const float*)d_in[1];
    const float* W_ih = (const float*)d_in[2];
    const float* b_ih = (const float*)d_in[3];
    const float* W_hh = (const float*)d_in[4];
    const float* b_hh = (const float*)d_in[5];
    const float* W1   = (const float*)d_in[6];
    const float* b1   = (const float*)d_in[7];
    const float* W2   = (const float*)d_in[8];
    const float* b2   = (const float*)d_in[9];
    const float* Wl1  = (const float*)d_in[10];
    const float* bl1  = (const float*)d_in[11];
    const float* Wmu  = (const float*)d_in[12];
    const float* bmu  = (const float*)d_in[13];
    float* out = (float*)d_out;

    char* ws = (char*)d_ws;
    _Float16* w1p   = (_Float16*)(ws);             // 64 KB
    _Float16* w2p   = (_Float16*)(ws + 65536);     // 64 KB
    _Float16* whh   = (_Float16*)(ws + 131072);    // 512 KB
    _Float16* wih   = (_Float16*)(ws + 655360);    // 64 KB
    _Float16* wl1p  = (_Float16*)(ws + 720896);    // 256 KB
    unsigned* hx    = (unsigned*)(ws + 1048576);   // 2 MB  (2 x 256 x 4KB slices)
    unsigned* flags = (unsigned*)(ws + 3145728);   // 1 KB (pad to 64 KB)
    _Float16* yg    = (_Float16*)(ws + 3211264);   // 105 MB (if available)

    const size_t need = 3211264 + (size_t)1024 * Tn * 512 * sizeof(_Float16);
    const int defer = (ws_size >= need) ? 1 : 0;

    odernn_init<<<256, 256, 0, stream>>>(W_ih, W_hh, W1, W2, Wl1,
                                         w1p, w2p, whh, wih, wl1p, flags);
    odernn_main<<<NWG, NTHR, 0, stream>>>(dt, x, b_ih, b_hh, b1, b2, bl1, Wmu, bmu,
                                          w1p, w2p, whh, wih, wl1p,
                                          hx, flags, yg, out, defer);
    if (defer)
        odernn_head<<<(1024 / 16) * Tn, 256, 0, stream>>>(yg, wl1p, bl1, Wmu, bmu, out);
}